// Round 1
// baseline (68.429 us; speedup 1.0000x reference)
//
#include <hip/hip_runtime.h>

#define SIDE 128
#define PI_F 3.14159265358979f
// Max window half-width: r = sqrt((ln(coef)+32)/c), coef<=2*4pi/0.5=50.27,
// c = pi*4pi/ff_b >= 2*pi^2 = 19.74  =>  r <= 1.35. Use 1.4 for safety.
// Terms outside |d|>1.4: coef*exp(-c*1.96) < 8e-16 each, 1e-11 summed -> negligible.
#define RMAX 1.4f
#define BLK 512

// One block per (batch, single row): grid (128,4) = 512 blocks = 2 blocks/CU
// (16 waves/CU). No compaction phase: each thread scans atoms strided (4
// rounds), and scatters its keepers directly, exec-masked. Waves with zero
// keepers in a round skip the scatter body via s_cbranch_execz. Fixed +-1.4
// window (superset of the per-factor radius window -> strictly more accurate),
// so no log/sqrt/div per factor. LDS is just one 512 B row accumulator.
__global__ void __launch_bounds__(BLK) potential_row(
        const float* __restrict__ coords,
        const float* __restrict__ ff_a,
        const float* __restrict__ ff_b,
        float* __restrict__ out,
        int A) {
    const int row = blockIdx.x;         // 0..127
    const int b   = blockIdx.y;
    const int t   = threadIdx.x;        // 0..511

    __shared__ float img[SIDE];         // 512 B row accumulator
    if (t < SIDE) img[t] = 0.0f;
    __syncthreads();

    const float* cb  = coords + (size_t)b * A * 3;
    const float  ylo = (float)row - RMAX;
    const float  yhi = (float)row + RMAX;

    for (int a = t; a < A; a += BLK) {          // 4 rounds at A=2048
        const float cx = cb[a * 3 + 0] + 64.0f;
        const float cy = cb[a * 3 + 1] + 64.0f;
        const bool keep = (cy >= ylo) & (cy <= yhi) &
                          (cx >= -RMAX) & (cx <= 127.0f + RMAX);
        if (!keep) continue;                    // exec-mask; execz skips body

        const float dy  = (float)row - cy;
        const float dy2 = dy * dy;
        const int j0 = max(0,        (int)ceilf(cx - RMAX));
        const int j1 = min(SIDE - 1, (int)floorf(cx + RMAX));  // <= 3 cols

        const float* fa = ff_a + a * 5;
        const float* fb = ff_b + a * 5;
        #pragma unroll
        for (int f = 0; f < 5; ++f) {
            const float invb = (4.0f * PI_F) / fb[f];
            const float coef = fa[f] * invb;    // peak amplitude
            const float c    = PI_F * invb;     // exponent scale
            const float wyi  = coef * __expf(-c * dy2);
            for (int j = j0; j <= j1; ++j) {
                const float dx = (float)j - cx;
                atomicAdd(&img[j], wyi * __expf(-c * dx * dx)); // ds_add
            }
        }
    }
    __syncthreads();

    // Coalesced store of the disjoint row (overwrites 0xAA poison).
    if (t < SIDE / 4) {                 // 32 float4 = 128 floats
        float4* ov = (float4*)(out + ((size_t)b * SIDE + row) * SIDE);
        ov[t] = ((const float4*)img)[t];
    }
}

extern "C" void kernel_launch(void* const* d_in, const int* in_sizes, int n_in,
                              void* d_out, int out_size, void* d_ws, size_t ws_size,
                              hipStream_t stream) {
    const float* coords = (const float*)d_in[0];
    const float* ffa    = (const float*)d_in[1];
    const float* ffb    = (const float*)d_in[2];
    float* out = (float*)d_out;

    int A = in_sizes[1] / 5;            // 2048 (in_sizes are element counts)
    int B = in_sizes[0] / (A * 3);      // 4

    dim3 grid(SIDE, B);                 // (128 rows, 4 batches) = 512 blocks
    potential_row<<<grid, BLK, 0, stream>>>(coords, ffa, ffb, out, A);
}

// Round 2
// 62.949 us; speedup vs baseline: 1.0871x; 1.0871x over previous
//
#include <hip/hip_runtime.h>

#define SIDE 128
#define PI_F 3.14159265358979f
// Max window half-width: r = sqrt((ln(coef)+32)/c), coef<=2*4pi/0.5=50.27,
// c = pi*4pi/ff_b >= 2*pi^2 = 19.74  =>  r <= 1.35. Use 1.4 for safety.
// Any term beyond |d|>1.4: coef*exp(-c*1.96) < 8e-16; summed < 1e-11. Negligible.
#define RMAX 1.4f
#define BLK 64

// Atom-parallel scatter: one thread per (batch, atom). All input reads are
// once-only and coalesced (ff: contiguous 20 B/lane; coords: 12 B stride).
// Fixed 3x3 window (ceil(c-1.4) .. +2 is always a superset of the true
// <=3-wide window; extra pixels contribute < 4e-18). Separable wx (x) wy
// accumulated in registers over the 5 factors, then <=9 predicated global
// atomicAdds. out is pre-zeroed by a memset node (atomic accumulation base +
// far-pixel value, where the reference's contribution is < 1e-11).
// No LDS, no barriers, no per-block rescan of the atom list.
__global__ void __launch_bounds__(BLK) potential_scatter(
        const float* __restrict__ coords,
        const float* __restrict__ ff_a,
        const float* __restrict__ ff_b,
        float* __restrict__ out,
        int A) {
    const int a = blockIdx.x * BLK + threadIdx.x;
    const int b = blockIdx.y;
    if (a >= A) return;

    const float cx = coords[((size_t)b * A + a) * 3 + 0] + 64.0f;
    const float cy = coords[((size_t)b * A + a) * 3 + 1] + 64.0f;

    // whole window off-grid -> nothing to do
    if (cx < -RMAX || cx > (float)(SIDE - 1) + RMAX ||
        cy < -RMAX || cy > (float)(SIDE - 1) + RMAX) return;

    const int j0 = (int)ceilf(cx - RMAX);   // cols j0..j0+2 (superset window)
    const int i0 = (int)ceilf(cy - RMAX);   // rows i0..i0+2
    const float dx0 = (float)j0 - cx;
    const float dy0 = (float)i0 - cy;

    float acc[3][3] = {{0.f, 0.f, 0.f}, {0.f, 0.f, 0.f}, {0.f, 0.f, 0.f}};
    #pragma unroll
    for (int f = 0; f < 5; ++f) {
        const float fb   = ff_b[a * 5 + f];          // coalesced 20 B/lane
        const float invb = (4.0f * PI_F) / fb;
        const float coef = ff_a[a * 5 + f] * invb;   // peak amplitude
        const float c    = PI_F * invb;              // exponent scale
        float wx[3], wy[3];
        #pragma unroll
        for (int k = 0; k < 3; ++k) {
            const float dx = dx0 + (float)k;
            const float dy = dy0 + (float)k;
            wx[k] = __expf(-c * dx * dx);
            wy[k] = coef * __expf(-c * dy * dy);
        }
        #pragma unroll
        for (int ii = 0; ii < 3; ++ii)
            #pragma unroll
            for (int jj = 0; jj < 3; ++jj)
                acc[ii][jj] += wy[ii] * wx[jj];
    }

    float* ob = out + (size_t)b * SIDE * SIDE;
    #pragma unroll
    for (int ii = 0; ii < 3; ++ii) {
        const int i = i0 + ii;
        if (i < 0 || i >= SIDE) continue;
        #pragma unroll
        for (int jj = 0; jj < 3; ++jj) {
            const int j = j0 + jj;
            if (j < 0 || j >= SIDE) continue;
            atomicAdd(&ob[i * SIDE + j], acc[ii][jj]);  // ~26 adds max/pixel
        }
    }
}

extern "C" void kernel_launch(void* const* d_in, const int* in_sizes, int n_in,
                              void* d_out, int out_size, void* d_ws, size_t ws_size,
                              hipStream_t stream) {
    const float* coords = (const float*)d_in[0];
    const float* ffa    = (const float*)d_in[1];
    const float* ffb    = (const float*)d_in[2];
    float* out = (float*)d_out;

    int A = in_sizes[1] / 5;            // 2048 (in_sizes are element counts)
    int B = in_sizes[0] / (A * 3);      // 4

    // Zero the (poisoned) output: atomic accumulation base. Graph-capture-safe.
    hipMemsetAsync(out, 0, (size_t)B * SIDE * SIDE * sizeof(float), stream);

    dim3 grid((A + BLK - 1) / BLK, B);  // (32, 4) = 128 single-wave blocks
    potential_scatter<<<grid, BLK, 0, stream>>>(coords, ffa, ffb, out, A);
}